// Round 5
// baseline (562.164 us; speedup 1.0000x reference)
//
#include <hip/hip_runtime.h>
#include <hip/hip_bf16.h>

#define N_USERS   50000
#define N_ITEMS   50000
#define N_ENT     100000
#define NE        2000000
#define NNI       1000000
#define DD        64

#define PART_E    (N_ENT / 8)    // 12500 entity rows per XCD partition
#define PART_I    (N_ITEMS / 8)  // 6250

#define NB_E      ((N_ENT  + 255) / 256)   // 391
#define NB_C      ((N_ITEMS + 255) / 256)  // 196
#define NB_R      ((N_USERS + 255) / 256)  // 196

#define ECAP_E    262144   // per-bucket staging capacity, edges (mean 250000, +25 sigma)
#define ECAP_M    131072   // per-bucket staging capacity, mat   (mean 125000)
#define CHUNK     4096
#define CAPB      640      // LDS per-bucket capacity (mean 512 per chunk)

// ---------------------------------------------------------------------------
// Pass 1a: bucket edges by destination XCD partition (head/PART_E).
// LDS-staged, chunked coalesced flushes. SoA: key (head), val (tail|etype<<17).
// ---------------------------------------------------------------------------
__global__ __launch_bounds__(256) void bucket_edge_kernel(
        const int* __restrict__ head, const int* __restrict__ tail,
        const int* __restrict__ etype,
        int* __restrict__ stK, int* __restrict__ stV, int* __restrict__ cur) {
    __shared__ int bufK[8][CAPB];
    __shared__ int bufV[8][CAPB];
    __shared__ int lcnt[8];
    __shared__ int gbase[8];
    const int tid = threadIdx.x;
    for (int cs = blockIdx.x * CHUNK; cs < NE; cs += gridDim.x * CHUNK) {
        if (tid < 8) lcnt[tid] = 0;
        __syncthreads();
        const int ce = min(cs + CHUNK, NE);
        for (int i = cs + tid; i < ce; i += 256) {
            const int h = __builtin_nontemporal_load(head + i);
            const int t = __builtin_nontemporal_load(tail + i);
            const int r = __builtin_nontemporal_load(etype + i);
            const int b = h / PART_E;
            const int v = t | (r << 17);
            const int p = atomicAdd(&lcnt[b], 1);
            if (p < CAPB) { bufK[b][p] = h; bufV[b][p] = v; }
            else {
                const int g = atomicAdd(&cur[b], 1);
                stK[(size_t)b * ECAP_E + g] = h;
                stV[(size_t)b * ECAP_E + g] = v;
            }
        }
        __syncthreads();
        if (tid < 8) gbase[tid] = atomicAdd(&cur[tid], min(lcnt[tid], CAPB));
        __syncthreads();
        for (int b = 0; b < 8; ++b) {
            const int n = min(lcnt[b], CAPB);
            int* dK = stK + (size_t)b * ECAP_E + gbase[b];
            int* dV = stV + (size_t)b * ECAP_E + gbase[b];
            for (int j = tid; j < n; j += 256) { dK[j] = bufK[b][j]; dV[j] = bufV[b][j]; }
        }
        __syncthreads();
    }
}

// ---------------------------------------------------------------------------
// Pass 1b: bucket mat entries twice (by col for col-CSR, by row for row-CSR).
// Entry packed: key<<16 | payload (both < 50000 < 2^16).
// ---------------------------------------------------------------------------
__global__ __launch_bounds__(256) void bucket_mat_kernel(
        const int* __restrict__ mrow, const int* __restrict__ mcol,
        int* __restrict__ stC, int* __restrict__ curC,
        int* __restrict__ stR, int* __restrict__ curR) {
    __shared__ int bufc[8][CAPB];
    __shared__ int bufr[8][CAPB];
    __shared__ int lc[8], lr[8], gc[8], gr[8];
    const int tid = threadIdx.x;
    for (int cs = blockIdx.x * CHUNK; cs < NNI; cs += gridDim.x * CHUNK) {
        if (tid < 8) { lc[tid] = 0; lr[tid] = 0; }
        __syncthreads();
        const int ce = min(cs + CHUNK, NNI);
        for (int i = cs + tid; i < ce; i += 256) {
            const int r = __builtin_nontemporal_load(mrow + i);
            const int c = __builtin_nontemporal_load(mcol + i);
            const int vc = (int)(((unsigned)c << 16) | (unsigned)r);
            const int bc = c / PART_I;
            int p = atomicAdd(&lc[bc], 1);
            if (p < CAPB) bufc[bc][p] = vc;
            else stC[(size_t)bc * ECAP_M + atomicAdd(&curC[bc], 1)] = vc;
            const int vr = (int)(((unsigned)r << 16) | (unsigned)c);
            const int br = r / PART_I;
            p = atomicAdd(&lr[br], 1);
            if (p < CAPB) bufr[br][p] = vr;
            else stR[(size_t)br * ECAP_M + atomicAdd(&curR[br], 1)] = vr;
        }
        __syncthreads();
        if (tid < 8)       gc[tid]     = atomicAdd(&curC[tid],     min(lc[tid],     CAPB));
        else if (tid < 16) gr[tid - 8] = atomicAdd(&curR[tid - 8], min(lr[tid - 8], CAPB));
        __syncthreads();
        for (int b = 0; b < 8; ++b) {
            int n = min(lc[b], CAPB);
            int* d = stC + (size_t)b * ECAP_M + gc[b];
            for (int j = tid; j < n; j += 256) d[j] = bufc[b][j];
            n = min(lr[b], CAPB);
            d = stR + (size_t)b * ECAP_M + gr[b];
            for (int j = tid; j < n; j += 256) d[j] = bufr[b][j];
        }
        __syncthreads();
    }
}

// ---------------------------------------------------------------------------
// Pass 2: XCD-local histograms from staged buckets (1x read, nt loads).
// ---------------------------------------------------------------------------
__global__ void hist_edge_local(const int* __restrict__ stK,
                                const int* __restrict__ cur,
                                int* __restrict__ cnt) {
    const int part = blockIdx.x & 7;
    const int n = cur[part];
    const int* s = stK + (size_t)part * ECAP_E;
    int i = (blockIdx.x >> 3) * blockDim.x + threadIdx.x;
    const int st = (gridDim.x >> 3) * blockDim.x;
    for (; i < n; i += st) atomicAdd(&cnt[__builtin_nontemporal_load(s + i)], 1);
}

__global__ void hist_mat_local(const int* __restrict__ stC, const int* __restrict__ curC,
                               int* __restrict__ cnt_c,
                               const int* __restrict__ stR, const int* __restrict__ curR,
                               int* __restrict__ cnt_r) {
    const int part = blockIdx.x & 7;
    const int stp = (gridDim.x >> 3) * blockDim.x;
    const int i0 = (blockIdx.x >> 3) * blockDim.x + threadIdx.x;
    int n = curC[part];
    const int* s = stC + (size_t)part * ECAP_M;
    for (int i = i0; i < n; i += stp)
        atomicAdd(&cnt_c[(unsigned)__builtin_nontemporal_load(s + i) >> 16], 1);
    n = curR[part];
    s = stR + (size_t)part * ECAP_M;
    for (int i = i0; i < n; i += stp)
        atomicAdd(&cnt_r[(unsigned)__builtin_nontemporal_load(s + i) >> 16], 1);
}

// ---------------------------------------------------------------------------
// Fused 3-segment exclusive scan (unchanged).
// ---------------------------------------------------------------------------
__global__ void scan1_all_kernel(const int* __restrict__ cnt_e,
                                 const int* __restrict__ cnt_c,
                                 const int* __restrict__ cnt_r,
                                 int* __restrict__ off_e, int* __restrict__ off_c,
                                 int* __restrict__ off_r,
                                 int* __restrict__ bs_e, int* __restrict__ bs_c,
                                 int* __restrict__ bs_r) {
    __shared__ int s[256];
    const int b = blockIdx.x;
    const int* cnt; int* off; int* bs; int n; int blk;
    if (b < NB_E)            { cnt = cnt_e; off = off_e; bs = bs_e; n = N_ENT;   blk = b; }
    else if (b < NB_E + NB_C){ cnt = cnt_c; off = off_c; bs = bs_c; n = N_ITEMS; blk = b - NB_E; }
    else                     { cnt = cnt_r; off = off_r; bs = bs_r; n = N_USERS; blk = b - NB_E - NB_C; }
    const int tid = threadIdx.x;
    const int gi = blk * 256 + tid;
    const int x = (gi < n) ? cnt[gi] : 0;
    s[tid] = x; __syncthreads();
    for (int d = 1; d < 256; d <<= 1) {
        const int v = (tid >= d) ? s[tid - d] : 0;
        __syncthreads();
        s[tid] += v;
        __syncthreads();
    }
    if (gi < n) off[gi] = s[tid] - x;
    if (tid == 255) bs[blk] = s[255];
}

__global__ void scan2_all_kernel(int* __restrict__ bs_e, int* __restrict__ bs_c,
                                 int* __restrict__ bs_r) {
    __shared__ int s[512];
    int* bs; int nb;
    if (blockIdx.x == 0)      { bs = bs_e; nb = NB_E; }
    else if (blockIdx.x == 1) { bs = bs_c; nb = NB_C; }
    else                      { bs = bs_r; nb = NB_R; }
    const int tid = threadIdx.x;
    const int x = (tid < nb) ? bs[tid] : 0;
    s[tid] = x; __syncthreads();
    for (int d = 1; d < 512; d <<= 1) {
        const int v = (tid >= d) ? s[tid - d] : 0;
        __syncthreads();
        s[tid] += v;
        __syncthreads();
    }
    if (tid < nb) bs[tid] = s[tid] - x;
}

__global__ void scan3_all_kernel(int* __restrict__ off_e, int* __restrict__ off_c,
                                 int* __restrict__ off_r,
                                 const int* __restrict__ bs_e,
                                 const int* __restrict__ bs_c,
                                 const int* __restrict__ bs_r,
                                 int* __restrict__ nxt_e, int* __restrict__ nxt_c,
                                 int* __restrict__ nxt_r) {
    const int b = blockIdx.x;
    int* off; const int* bs; int* nxt; int n; int blk; int total;
    if (b < NB_E)            { off = off_e; bs = bs_e; nxt = nxt_e; n = N_ENT;   blk = b;               total = NE; }
    else if (b < NB_E + NB_C){ off = off_c; bs = bs_c; nxt = nxt_c; n = N_ITEMS; blk = b - NB_E;        total = NNI; }
    else                     { off = off_r; bs = bs_r; nxt = nxt_r; n = N_USERS; blk = b - NB_E - NB_C; total = NNI; }
    const int gi = blk * 256 + threadIdx.x;
    if (gi < n) {
        const int v = off[gi] + bs[blk];
        off[gi] = v;
        nxt[gi] = v;
    }
    if (blk == 0 && threadIdx.x == 0) off[n] = total;
}

// ---------------------------------------------------------------------------
// Pass 3: XCD-local fills from staged buckets.
// ---------------------------------------------------------------------------
__global__ void fill_edge_local(const int* __restrict__ stK, const int* __restrict__ stV,
                                const int* __restrict__ cur,
                                int* __restrict__ nxt, int* __restrict__ ids) {
    const int part = blockIdx.x & 7;
    const int n = cur[part];
    const int* sK = stK + (size_t)part * ECAP_E;
    const int* sV = stV + (size_t)part * ECAP_E;
    int i = (blockIdx.x >> 3) * blockDim.x + threadIdx.x;
    const int st = (gridDim.x >> 3) * blockDim.x;
    for (; i < n; i += st) {
        const int h = __builtin_nontemporal_load(sK + i);
        const int v = __builtin_nontemporal_load(sV + i);
        const int p = atomicAdd(&nxt[h], 1);
        ids[p] = v;
    }
}

__global__ void fill_mat_local(const int* __restrict__ stC, const int* __restrict__ curC,
                               int* __restrict__ nxt_c, int* __restrict__ ids_c,
                               const int* __restrict__ stR, const int* __restrict__ curR,
                               int* __restrict__ nxt_r, int* __restrict__ ids_r) {
    const int part = blockIdx.x & 7;
    const int stp = (gridDim.x >> 3) * blockDim.x;
    const int i0 = (blockIdx.x >> 3) * blockDim.x + threadIdx.x;
    int n = curC[part];
    const int* s = stC + (size_t)part * ECAP_M;
    for (int i = i0; i < n; i += stp) {
        const unsigned u = (unsigned)__builtin_nontemporal_load(s + i);
        const int p = atomicAdd(&nxt_c[u >> 16], 1);
        ids_c[p] = (int)(u & 0xFFFF);
    }
    n = curR[part];
    s = stR + (size_t)part * ECAP_M;
    for (int i = i0; i < n; i += stp) {
        const unsigned u = (unsigned)__builtin_nontemporal_load(s + i);
        const int p = atomicAdd(&nxt_r[u >> 16], 1);
        ids_r[p] = (int)(u & 0xFFFF);
    }
}

// ---------------------------------------------------------------------------
// Fallback mat hist/fill (round-4 partitioned 8x re-read) if ws too small.
// ---------------------------------------------------------------------------
__global__ void hist_mat_kernel(const int* __restrict__ mrow,
                                const int* __restrict__ mcol,
                                int* __restrict__ cnt_c,
                                int* __restrict__ cnt_r) {
    const int part = blockIdx.x & 7;
    const int lo = part * PART_I, hi = lo + PART_I;
    int i = (blockIdx.x >> 3) * blockDim.x + threadIdx.x;
    const int st = (gridDim.x >> 3) * blockDim.x;
    for (; i < NNI; i += st) {
        const int c = mcol[i];
        if (c >= lo && c < hi) atomicAdd(&cnt_c[c], 1);
        const int r = mrow[i];
        if (r >= lo && r < hi) atomicAdd(&cnt_r[r], 1);
    }
}

__global__ void fill_mat_kernel(const int* __restrict__ mrow,
                                const int* __restrict__ mcol,
                                int* __restrict__ nxt_c, int* __restrict__ ids_c,
                                int* __restrict__ nxt_r, int* __restrict__ ids_r) {
    const int part = blockIdx.x & 7;
    const int lo = part * PART_I, hi = lo + PART_I;
    int i = (blockIdx.x >> 3) * blockDim.x + threadIdx.x;
    const int st = (gridDim.x >> 3) * blockDim.x;
    for (; i < NNI; i += st) {
        const int c = mcol[i];
        const int r = mrow[i];
        if (c >= lo && c < hi) { const int p = atomicAdd(&nxt_c[c], 1); ids_c[p] = r; }
        if (r >= lo && r < hi) { const int p = atomicAdd(&nxt_r[r], 1); ids_r[p] = c; }
    }
}

// ---------------------------------------------------------------------------
// Pull aggregations (unchanged).
// ---------------------------------------------------------------------------
__global__ void pull_entity_kernel(const float* __restrict__ ent,
                                   const float* __restrict__ wgt,
                                   const int* __restrict__ off,
                                   const int* __restrict__ ids,
                                   float* __restrict__ out) {
    const int lane = threadIdx.x & 63;
    const int wid = (blockIdx.x * blockDim.x + threadIdx.x) >> 6;
    if (wid >= N_ENT) return;
    const int beg = off[wid], end = off[wid + 1];
    float acc = 0.f;
    for (int base = beg; base < end; base += 64) {
        const int k = base + lane;
        int v = 0;
        if (k < end) v = ids[k];
        const int n = min(64, end - base);
        int kk = 0;
        for (; kk + 4 <= n; kk += 4) {
            const int v0 = __shfl(v, kk),     v1 = __shfl(v, kk + 1);
            const int v2 = __shfl(v, kk + 2), v3 = __shfl(v, kk + 3);
            const float a0 = ent[(size_t)(v0 & 0x1FFFF) * DD + lane] * wgt[(v0 >> 17) * DD + lane];
            const float a1 = ent[(size_t)(v1 & 0x1FFFF) * DD + lane] * wgt[(v1 >> 17) * DD + lane];
            const float a2 = ent[(size_t)(v2 & 0x1FFFF) * DD + lane] * wgt[(v2 >> 17) * DD + lane];
            const float a3 = ent[(size_t)(v3 & 0x1FFFF) * DD + lane] * wgt[(v3 >> 17) * DD + lane];
            acc += a0 + a1 + a2 + a3;
        }
        for (; kk < n; ++kk) {
            const int vv = __shfl(v, kk);
            acc += ent[(size_t)(vv & 0x1FFFF) * DD + lane] * wgt[(vv >> 17) * DD + lane];
        }
    }
    const float d = (float)(end - beg);
    out[(size_t)wid * DD + lane] = acc / fmaxf(d, 1.0f);
}

__global__ void pull_iu_kernel(const float* __restrict__ uemb,
                               const float* __restrict__ wgt,
                               const int* __restrict__ off,
                               const int* __restrict__ ids,
                               float* __restrict__ iu_out) {
    const int lane = threadIdx.x & 63;
    const int wid = (blockIdx.x * blockDim.x + threadIdx.x) >> 6;
    if (wid >= N_ITEMS) return;
    const float w0 = wgt[lane];
    const int beg = off[wid], end = off[wid + 1];
    float acc = 0.f;
    for (int base = beg; base < end; base += 64) {
        const int k = base + lane;
        int v = 0;
        if (k < end) v = ids[k];
        const int n = min(64, end - base);
        int kk = 0;
        for (; kk + 4 <= n; kk += 4) {
            const int v0 = __shfl(v, kk),     v1 = __shfl(v, kk + 1);
            const int v2 = __shfl(v, kk + 2), v3 = __shfl(v, kk + 3);
            acc += uemb[(size_t)v0 * DD + lane] + uemb[(size_t)v1 * DD + lane]
                 + uemb[(size_t)v2 * DD + lane] + uemb[(size_t)v3 * DD + lane];
        }
        for (; kk < n; ++kk) {
            const int vv = __shfl(v, kk);
            acc += uemb[(size_t)vv * DD + lane];
        }
    }
    const float d = (float)(end - beg);
    iu_out[(size_t)wid * DD + lane] = acc * w0 / fmaxf(d, 1.0f);
}

__global__ void pull_user_kernel(const float* __restrict__ fus,
                                 const int* __restrict__ off,
                                 const int* __restrict__ ids,
                                 float* __restrict__ uout) {
    const int lane = threadIdx.x & 63;
    const int wid = (blockIdx.x * blockDim.x + threadIdx.x) >> 6;
    if (wid >= N_USERS) return;
    const int beg = off[wid], end = off[wid + 1];
    float acc = 0.f;
    for (int base = beg; base < end; base += 64) {
        const int k = base + lane;
        int v = 0;
        if (k < end) v = ids[k];
        const int n = min(64, end - base);
        int kk = 0;
        for (; kk + 4 <= n; kk += 4) {
            const int v0 = __shfl(v, kk),     v1 = __shfl(v, kk + 1);
            const int v2 = __shfl(v, kk + 2), v3 = __shfl(v, kk + 3);
            acc += fus[(size_t)v0 * DD + lane] + fus[(size_t)v1 * DD + lane]
                 + fus[(size_t)v2 * DD + lane] + fus[(size_t)v3 * DD + lane];
        }
        for (; kk < n; ++kk) {
            const int vv = __shfl(v, kk);
            acc += fus[(size_t)vv * DD + lane];
        }
    }
    uout[(size_t)wid * DD + lane] = acc;
}

// ---------------------------------------------------------------------------
// Gate + fusion (unchanged).
// ---------------------------------------------------------------------------
__global__ void gate_fusion_kernel(float* __restrict__ kg_fus,
                                   const float* __restrict__ iu,
                                   const float* __restrict__ g1,
                                   const float* __restrict__ g2) {
    __shared__ float G1[64 * 65];
    __shared__ float G2[64 * 65];
    __shared__ float xs1[4][64];
    __shared__ float xs2[4][64];

    const int tid = threadIdx.x;
    for (int i = tid; i < 64 * 64; i += 256) {
        const int r = i >> 6, c = i & 63;
        G1[r * 65 + c] = g1[i];
        G2[r * 65 + c] = g2[i];
    }

    const int il = tid >> 6;
    const int j = tid & 63;
    const int item = blockIdx.x * 4 + il;

    const float x1 = kg_fus[(size_t)item * DD + j];
    const float x2 = iu[(size_t)item * DD + j];
    xs1[il][j] = x1;
    xs2[il][j] = x2;
    __syncthreads();

    float s = 0.0f;
    #pragma unroll
    for (int k = 0; k < 64; ++k) {
        s += xs1[il][k] * G1[j * 65 + k];
        s += xs2[il][k] * G2[j * 65 + k];
    }
    const float gi = 1.0f / (1.0f + __expf(-s));
    kg_fus[(size_t)item * DD + j] = gi * x1 + (1.0f - gi) * x2;
}

extern "C" void kernel_launch(void* const* d_in, const int* in_sizes, int n_in,
                              void* d_out, int out_size, void* d_ws, size_t ws_size,
                              hipStream_t stream) {
    const float* entity_emb = (const float*)d_in[0];
    const float* user_emb   = (const float*)d_in[1];
    const int*   edge_index = (const int*)d_in[2];
    const int*   edge_type  = (const int*)d_in[3];
    const int*   mat_row    = (const int*)d_in[4];
    const int*   mat_col    = (const int*)d_in[5];
    const float* weight     = (const float*)d_in[7];
    const float* gate1_w    = (const float*)d_in[8];
    const float* gate2_w    = (const float*)d_in[9];

    float* out = (float*)d_out;
    float* out_fusion = out;                       // rows [0, 50000)
    float* out_entity = out;                       // rows [0, 100000)
    float* out_user   = out + (size_t)N_ENT * DD;  // temp i_u_agg, then user_agg

    // workspace layout (ints)
    int* W      = (int*)d_ws;
    int* cnt_e  = W;                       // 100000 (cnt block + cursors: one memset)
    int* cnt_c  = W + 100000;              // 50000
    int* cnt_r  = W + 150000;              // 50000
    int* cur_e  = W + 200000;              // 8
    int* cur_c  = W + 200008;              // 8
    int* cur_r  = W + 200016;              // 8
    int* off_e  = W + 200024;              // 100001
    int* off_c  = W + 300025;              // 50001
    int* off_r  = W + 350026;              // 50001
    int* nxt_e  = W + 400027;              // 100000
    int* nxt_c  = W + 500027;              // 50000
    int* nxt_r  = W + 550027;              // 50000
    int* bs_e   = W + 600027;              // 512
    int* bs_c   = W + 600539;              // 512
    int* bs_r   = W + 601051;              // 512
    int* ids_e  = W + 601563;              // 2000000
    int* ids_c  = W + 2601563;             // 1000000
    int* ids_r  = W + 3601563;             // 1000000
    int* st_ek  = W + 4601563;             // 8*262144 = 2097152
    int* st_ev  = W + 6698715;             // 2097152
    int* st_c   = W + 8795867;             // 8*131072 = 1048576 (optional)
    int* st_r   = W + 9844443;             // 1048576 (optional)
    const size_t need_full = (size_t)10893019 * sizeof(int);   // ~43.6 MB
    const bool mat_bucketed = (ws_size >= need_full);

    const int* head = edge_index;
    const int* tail = edge_index + NE;

    // zero counters + cursors (one contiguous 800 KB memset)
    (void)hipMemsetAsync(cnt_e, 0, (size_t)200024 * sizeof(int), stream);

    // pass 1: bucket by XCD partition
    bucket_edge_kernel<<<512, 256, 0, stream>>>(head, tail, edge_type, st_ek, st_ev, cur_e);
    if (mat_bucketed)
        bucket_mat_kernel<<<256, 256, 0, stream>>>(mat_row, mat_col, st_c, cur_c, st_r, cur_r);

    // pass 2: XCD-local histograms
    hist_edge_local<<<2048, 256, 0, stream>>>(st_ek, cur_e, cnt_e);
    if (mat_bucketed)
        hist_mat_local<<<2048, 256, 0, stream>>>(st_c, cur_c, cnt_c, st_r, cur_r, cnt_r);
    else
        hist_mat_kernel<<<2048, 256, 0, stream>>>(mat_row, mat_col, cnt_c, cnt_r);

    // scans
    scan1_all_kernel<<<NB_E + NB_C + NB_R, 256, 0, stream>>>(cnt_e, cnt_c, cnt_r,
                                                             off_e, off_c, off_r,
                                                             bs_e, bs_c, bs_r);
    scan2_all_kernel<<<3, 512, 0, stream>>>(bs_e, bs_c, bs_r);
    scan3_all_kernel<<<NB_E + NB_C + NB_R, 256, 0, stream>>>(off_e, off_c, off_r,
                                                             bs_e, bs_c, bs_r,
                                                             nxt_e, nxt_c, nxt_r);

    // pass 3: XCD-local fills
    fill_edge_local<<<2048, 256, 0, stream>>>(st_ek, st_ev, cur_e, nxt_e, ids_e);
    if (mat_bucketed)
        fill_mat_local<<<2048, 256, 0, stream>>>(st_c, cur_c, nxt_c, ids_c,
                                                 st_r, cur_r, nxt_r, ids_r);
    else
        fill_mat_kernel<<<2048, 256, 0, stream>>>(mat_row, mat_col,
                                                  nxt_c, ids_c, nxt_r, ids_r);

    // pull aggregations + gate
    pull_entity_kernel<<<N_ENT / 4, 256, 0, stream>>>(entity_emb, weight,
                                                      off_e, ids_e, out_entity);
    pull_iu_kernel<<<N_ITEMS / 4, 256, 0, stream>>>(user_emb, weight,
                                                    off_c, ids_c, out_user);
    gate_fusion_kernel<<<N_ITEMS / 4, 256, 0, stream>>>(out_fusion, out_user,
                                                        gate1_w, gate2_w);
    pull_user_kernel<<<N_USERS / 4, 256, 0, stream>>>(out_fusion,
                                                      off_r, ids_r, out_user);
}